// Round 6
// baseline (131.791 us; speedup 1.0000x reference)
//
#include <hip/hip_runtime.h>

// Reference-exact fp32 d2: no FMA contraction. d2 = (sqn+sqm) + dot' with
// dot' built from (-2x) pre-scaled m-points is bit-identical to the ref's
// (sqn+sqm) - 2*dot (power-of-2 scaling / negation commute with rounding).
#pragma clang fp contract(off)

#define NBATCH 256   // B*L
#define NPTS   512   // points per batch
#define JDIM   128   // logit dim
#define ROWS_T 16    // ypred rows per tile (16*512*4 = 32 KB), double-buffered
#define NTILE  (JDIM / ROWS_T)   // 8 tiles

// Grid: 512 blocks = 2 per batch; block b -> batch b>>1, point-half b&1.
// Phase A: thread owns 4 points (pbase..pbase+3), scans an m-eighth (64 m's).
// Phase B: thread (nl = t&255, role = t>>8) computes sim[n][pidx[role][nl]].
__global__ __launch_bounds__(512) void fused_loss_kernel(
    const float* __restrict__ ypred,   // [NBATCH, JDIM, NPTS]
    const float* __restrict__ xyz,     // [NBATCH, NPTS, 3]
    float* __restrict__ out)           // scalar accumulator (pre-zeroed)
{
    __shared__ float tiles[2][ROWS_T * NPTS];   // 2 x 32 KB
    __shared__ int   pidx[2][256];              // [argmax/argmin][local point]
    __shared__ float wred[8];

    const int t  = threadIdx.x;        // 0..511
    const int bl = blockIdx.x >> 1;
    const int h  = blockIdx.x & 1;     // point-half owned by this block

    const float* yp = ypred + (size_t)bl * JDIM * NPTS;

    // tile-0 ypred loads issued NOW; land during phase A (VMEM overlap)
    const float4* s0 = (const float4*)yp;
    float4 t0[4];
    #pragma unroll
    for (int u = 0; u < 4; ++u) t0[u] = s0[u * 512 + t];

    // ---- stage scaled xyz into tiles[0]: (-2x,-2y,-2z, sq), sq in ref order
    float4* xyzS = (float4*)tiles[0];           // 8 KB
    {
        const float* xp = xyz + (size_t)bl * NPTS * 3 + 3 * t;
        float x = xp[0], y = xp[1], z = xp[2];
        float sq = (x * x + y * y) + z * z;     // matches np.sum(x*x,-1)
        xyzS[t] = make_float4(-2.0f * x, -2.0f * y, -2.0f * z, sq);
    }

    // ---- own 4 points RAW from global: 12 consecutive floats = 3 float4
    const int g    = t & 63;           // point group within half
    const int sub  = t >> 6;           // m-subrange 0..7 (wave-uniform)
    const int pbase = h * 256 + g * 4;
    float ox[4], oy[4], oz[4], oq[4];
    {
        const float4* own = (const float4*)(xyz + (size_t)bl * NPTS * 3
                                                + (size_t)pbase * 3);
        float4 o0 = own[0], o1 = own[1], o2 = own[2];
        ox[0] = o0.x; oy[0] = o0.y; oz[0] = o0.z;
        ox[1] = o0.w; oy[1] = o1.x; oz[1] = o1.y;
        ox[2] = o1.z; oy[2] = o1.w; oz[2] = o2.x;
        ox[3] = o2.y; oy[3] = o2.z; oz[3] = o2.w;
        #pragma unroll
        for (int k = 0; k < 4; ++k)
            oq[k] = (ox[k] * ox[k] + oy[k] * oy[k]) + oz[k] * oz[k];
    }
    __syncthreads();

    // ---- Phase A: 64-m scan, 4 points per broadcast read ----
    const int mbase = sub * 64;
    float bmax[4], bmin[4]; int ima[4], imi[4];
    #pragma unroll
    for (int k = 0; k < 4; ++k) {
        bmax[k] = -1.0f; bmin[k] = 3.0e38f; ima[k] = mbase; imi[k] = mbase;
    }

    #pragma unroll 4
    for (int mm = 0; mm < 64; ++mm) {
        int m = mbase + mm;
        float4 qv = xyzS[m];           // wave-uniform -> LDS broadcast, 1 per 4 pts
        #pragma unroll
        for (int k = 0; k < 4; ++k) {
            float dt = (ox[k] * qv.x + oy[k] * qv.y) + oz[k] * qv.z; // == -2*dot
            float d2 = (oq[k] + qv.w) + dt;       // bits == ref d2 (pre-clamp)
            // argmax on unclamped d2: winner is large-positive, clamp irrelevant
            bool gt = d2 > bmax[k];
            ima[k] = gt ? m : ima[k];  bmax[k] = gt ? d2 : bmax[k];
            // argmin: ref masks clamp(d2)==0 <=> d2<=0; fold into compare
            bool lt = (d2 < bmin[k]) && (d2 > 0.0f);
            imi[k] = lt ? m : imi[k];  bmin[k] = lt ? d2 : bmin[k];
        }
    }

    // merge scratch aliased into tiles[1] (dead once phase B double-buffers)
    float* maxv = tiles[1];                      // [8][256]
    int*   maxi = (int*)(tiles[1] + 2048);
    float* minv = tiles[1] + 4096;
    int*   mini = (int*)(tiles[1] + 6144);
    #pragma unroll
    for (int k = 0; k < 4; ++k) {
        int idx = sub * 256 + 4 * g + k;
        maxv[idx] = bmax[k];  maxi[idx] = ima[k];
        minv[idx] = bmin[k];  mini[idx] = imi[k];
    }
    __syncthreads();

    // merge 8 m-subranges per point; ascending-sub strict compare keeps the
    // lowest m-range on exact ties -> first-occurrence. 256 thr max, 256 min.
    {
        const int pt = t & 255;
        if (t < 256) {
            float bv = maxv[pt]; int bi = maxi[pt];
            #pragma unroll
            for (int s = 1; s < 8; ++s) {
                float v = maxv[s * 256 + pt]; int i = maxi[s * 256 + pt];
                bool w = v > bv; bi = w ? i : bi; bv = w ? v : bv;
            }
            pidx[0][pt] = bi;
        } else {
            float sv = minv[pt]; int si = mini[pt];
            #pragma unroll
            for (int s = 1; s < 8; ++s) {
                float u = minv[s * 256 + pt]; int j = mini[s * 256 + pt];
                bool x = u < sv; si = x ? j : si; sv = x ? u : sv;
            }
            pidx[1][pt] = si;
        }
    }
    // write tile-0 (tiles[0]; xyzS reads all completed before prior barrier)
    {
        float4* dst = (float4*)tiles[0];
        #pragma unroll
        for (int u = 0; u < 4; ++u) dst[u * 512 + t] = t0[u];
    }
    __syncthreads();

    // ---- Phase B: double-buffered 16-row tiles, both operands from LDS ----
    const int role = t >> 8;           // 0 -> argmax partner, 1 -> argmin
    const int nlB  = t & 255;
    const int nB   = h * 256 + nlB;
    const int partner = pidx[role][nlB];

    float acc0 = 0.0f, acc1 = 0.0f;
    for (int tt = 0; tt < NTILE; ++tt) {
        float4 nx[4];
        if (tt + 1 < NTILE) {          // next tile's global loads before compute
            const float4* sn = (const float4*)(yp + (size_t)(tt + 1) * ROWS_T * NPTS);
            #pragma unroll
            for (int u = 0; u < 4; ++u) nx[u] = sn[u * 512 + t];
        }

        const float* buf = tiles[tt & 1];
        #pragma unroll
        for (int r = 0; r < ROWS_T; r += 2) {
            float a0 = buf[r * NPTS + nB];              // stride-1, conflict-free
            float p0 = buf[r * NPTS + partner];         // random gather
            float a1 = buf[(r + 1) * NPTS + nB];
            float p1 = buf[(r + 1) * NPTS + partner];
            acc0 = fmaf(a0, p0, acc0);
            acc1 = fmaf(a1, p1, acc1);
        }

        if (tt + 1 < NTILE) {
            float4* dst = (float4*)tiles[(tt + 1) & 1];
            #pragma unroll
            for (int u = 0; u < 4; ++u) dst[u * 512 + t] = nx[u];
        }
        __syncthreads();
    }

    // signed contribution: role 0 adds sim@max, role 1 subtracts sim@min
    float c = role ? -(acc0 + acc1) : (acc0 + acc1);
    #pragma unroll
    for (int off = 32; off > 0; off >>= 1)
        c += __shfl_down(c, off);
    if ((t & 63) == 0) wred[t >> 6] = c;
    __syncthreads();
    if (t == 0) {
        float s = 0.0f;
        #pragma unroll
        for (int w = 0; w < 8; ++w) s += wred[w];
        atomicAdd(out, s * (1.0f / (float)(NBATCH * NPTS)));
    }
}

extern "C" void kernel_launch(void* const* d_in, const int* in_sizes, int n_in,
                              void* d_out, int out_size, void* d_ws, size_t ws_size,
                              hipStream_t stream) {
    const float* ypred = (const float*)d_in[0];   // [8,32,128,512] f32
    const float* xyz   = (const float*)d_in[1];   // [8,32,512,3]  f32
    float* out         = (float*)d_out;           // scalar

    // d_out is re-poisoned before every launch; zero it (capture-legal).
    hipMemsetAsync(out, 0, sizeof(float), stream);
    fused_loss_kernel<<<2 * NBATCH, 512, 0, stream>>>(ypred, xyz, out);
}

// Round 7
// 115.788 us; speedup vs baseline: 1.1382x; 1.1382x over previous
//
#include <hip/hip_runtime.h>

// Reference-exact fp32 d2: no FMA contraction. d2 = (sqn+sqm) + dot' with
// dot' built from (-2x) pre-scaled m-points is bit-identical to the ref's
// (sqn+sqm) - 2*dot (power-of-2 scaling / negation commute with rounding).
// Self-distance: dt(n,n) = -2*sq_n exactly, so d2(n,n) == 0 exactly.
#pragma clang fp contract(off)

#define NBATCH 256   // B*L
#define NPTS   512   // points per batch
#define JDIM   128   // logit dim
#define NPAIR  (NBATCH * NPTS)   // 131072

// ---------------- K1: per-point argmax / masked-argmin of d2 ----------------
// Grid 1024 = 4 blocks/batch (128 points each). Block 512 thr, 40 KB LDS ->
// 4 blocks/CU, 32 waves. Thread t: point-group g = t&31 (4 pts), m-subrange
// s = t>>5 (32 m's). One 2-address LDS broadcast read feeds 4 d2's.
__global__ __launch_bounds__(512) void argmm_kernel(
    const float* __restrict__ xyz,   // [NBATCH, NPTS, 3]
    int* __restrict__ pmax,          // [NBATCH*NPTS]
    int* __restrict__ pmin)          // [NBATCH*NPTS]
{
    __shared__ float4 xyzS[NPTS];            // scaled (-2x,-2y,-2z, sq) : 8 KB
    __shared__ float mv[16][128];  __shared__ int mi[16][128];   // 16 KB
    __shared__ float nv[16][128];  __shared__ int ni[16][128];   // 16 KB

    const int t  = threadIdx.x;
    const int bl = blockIdx.x >> 2;
    const int qq = blockIdx.x & 3;           // point-quarter of this block
    const float* xp = xyz + (size_t)bl * NPTS * 3;

    // stage all 512 points, scaled; sq computed in ref order from raw values
    {
        float x = xp[3 * t], y = xp[3 * t + 1], z = xp[3 * t + 2];
        float sq = (x * x + y * y) + z * z;  // matches np.sum(x*x,-1)
        xyzS[t] = make_float4(-2.0f * x, -2.0f * y, -2.0f * z, sq);
    }

    // own 4 points raw from global: 12 consecutive floats = 3 float4
    const int g = t & 31, s = t >> 5;
    const int pbase = qq * 128 + g * 4;
    float ox[4], oy[4], oz[4], oq[4];
    {
        const float4* own = (const float4*)(xp + 3 * pbase);
        float4 o0 = own[0], o1 = own[1], o2 = own[2];
        ox[0] = o0.x; oy[0] = o0.y; oz[0] = o0.z;
        ox[1] = o0.w; oy[1] = o1.x; oz[1] = o1.y;
        ox[2] = o1.z; oy[2] = o1.w; oz[2] = o2.x;
        ox[3] = o2.y; oy[3] = o2.z; oz[3] = o2.w;
        #pragma unroll
        for (int k = 0; k < 4; ++k)
            oq[k] = (ox[k] * ox[k] + oy[k] * oy[k]) + oz[k] * oz[k];
    }
    __syncthreads();

    const int mbase = s * 32;
    float bmax[4], bmin[4]; int ima[4], imi[4];
    #pragma unroll
    for (int k = 0; k < 4; ++k) {
        bmax[k] = -1.0f; bmin[k] = 3.0e38f; ima[k] = mbase; imi[k] = mbase;
    }

    #pragma unroll 8
    for (int mm = 0; mm < 32; ++mm) {
        int m = mbase + mm;
        float4 qv = xyzS[m];                 // 2 addrs/wave -> free broadcast
        #pragma unroll
        for (int k = 0; k < 4; ++k) {
            float dt = (ox[k] * qv.x + oy[k] * qv.y) + oz[k] * qv.z; // == -2*dot
            float d2 = (oq[k] + qv.w) + dt;  // bits == ref d2 (pre-clamp)
            bool gt = d2 > bmax[k];          // strict -> first occurrence
            ima[k] = gt ? m : ima[k];  bmax[k] = gt ? d2 : bmax[k];
            // ref masks clamp(d2)==0 <=> d2<=0; fold into the compare
            bool lt = (d2 < bmin[k]) && (d2 > 0.0f);
            imi[k] = lt ? m : imi[k];  bmin[k] = lt ? d2 : bmin[k];
        }
    }

    #pragma unroll
    for (int k = 0; k < 4; ++k) {
        int pt = g * 4 + k;
        mv[s][pt] = bmax[k];  mi[s][pt] = ima[k];
        nv[s][pt] = bmin[k];  ni[s][pt] = imi[k];
    }
    __syncthreads();

    // merge 16 ascending-m subranges; strict compare keeps lowest m-range on
    // exact ties -> first-occurrence. 128 threads max, 128 threads min.
    if (t < 256) {
        const int pt = t & 127;
        const int out_idx = bl * NPTS + qq * 128 + pt;
        if (t < 128) {
            float bv = mv[0][pt]; int bi = mi[0][pt];
            #pragma unroll
            for (int ss = 1; ss < 16; ++ss) {
                float v = mv[ss][pt]; int i = mi[ss][pt];
                bool w = v > bv; bi = w ? i : bi; bv = w ? v : bv;
            }
            pmax[out_idx] = bi;
        } else {
            float sv = nv[0][pt]; int si = ni[0][pt];
            #pragma unroll
            for (int ss = 1; ss < 16; ++ss) {
                float u = nv[ss][pt]; int j = ni[ss][pt];
                bool x = u < sv; si = x ? j : si; sv = x ? u : sv;
            }
            pmin[out_idx] = si;
        }
    }
}

// ---------------- K2: sim gathers, j-chunked, one barrier per block --------
// Grid 2048 = 256 batches x 8 chunks of 16 ypred rows. Block 512 thr: thread
// t owns point n=t; reads a once, gathers both partners. ypred read exactly
// once from HBM chip-wide -> streaming-bound.
__global__ __launch_bounds__(512) void sim_kernel(
    const float* __restrict__ ypred,   // [NBATCH, JDIM, NPTS]
    const int* __restrict__ pmax,
    const int* __restrict__ pmin,
    float* __restrict__ partials)      // [2048]
{
    __shared__ float L[16 * NPTS];     // 32 KB tile
    __shared__ float wred[8];

    const int t  = threadIdx.x;
    const int bl = blockIdx.x >> 3;
    const int c  = blockIdx.x & 7;     // j-chunk

    // partner indices: issue early, land under the staging loads
    const int pma = pmax[bl * NPTS + t];
    const int pmi = pmin[bl * NPTS + t];

    const float4* src = (const float4*)(ypred + (size_t)bl * JDIM * NPTS
                                              + (size_t)c * 16 * NPTS);
    float4 v0 = src[t], v1 = src[512 + t], v2 = src[1024 + t], v3 = src[1536 + t];
    float4* dst = (float4*)L;
    dst[t] = v0;  dst[512 + t] = v1;  dst[1024 + t] = v2;  dst[1536 + t] = v3;
    __syncthreads();

    float accP = 0.0f, accM = 0.0f;
    #pragma unroll
    for (int r = 0; r < 16; ++r) {
        float a  = L[r * NPTS + t];      // stride-1, conflict-free
        float b  = L[r * NPTS + pma];    // random gather, ~2-way (free)
        float cm = L[r * NPTS + pmi];
        accP = fmaf(a, b, accP);
        accM = fmaf(a, cm, accM);
    }

    float d = accP - accM;
    #pragma unroll
    for (int off = 32; off > 0; off >>= 1)
        d += __shfl_down(d, off);
    if ((t & 63) == 0) wred[t >> 6] = d;
    __syncthreads();
    if (t == 0) {
        float ssum = 0.0f;
        #pragma unroll
        for (int w = 0; w < 8; ++w) ssum += wred[w];
        partials[blockIdx.x] = ssum;
    }
}

// ---------------- K3: final mean over 2048 partials -------------------------
__global__ __launch_bounds__(1024) void reduce_mean_kernel(
    const float* __restrict__ partials, float* __restrict__ out)
{
    const int t = threadIdx.x;
    float v = partials[t] + partials[t + 1024];
    #pragma unroll
    for (int off = 32; off > 0; off >>= 1)
        v += __shfl_down(v, off);

    __shared__ float w[16];
    if ((t & 63) == 0) w[t >> 6] = v;
    __syncthreads();
    if (t == 0) {
        float s = 0.0f;
        #pragma unroll
        for (int i = 0; i < 16; ++i) s += w[i];
        out[0] = s * (1.0f / (float)NPAIR);
    }
}

extern "C" void kernel_launch(void* const* d_in, const int* in_sizes, int n_in,
                              void* d_out, int out_size, void* d_ws, size_t ws_size,
                              hipStream_t stream) {
    const float* ypred = (const float*)d_in[0];   // [8,32,128,512] f32
    const float* xyz   = (const float*)d_in[1];   // [8,32,512,3]  f32

    // ws: pmax[131072] ints, pmin[131072] ints, partials[2048] floats (~1.06 MB)
    int*   pmax     = (int*)d_ws;
    int*   pmin     = pmax + NPAIR;
    float* partials = (float*)(pmin + NPAIR);
    float* out      = (float*)d_out;

    argmm_kernel<<<4 * NBATCH, 512, 0, stream>>>(xyz, pmax, pmin);
    sim_kernel<<<8 * NBATCH, 512, 0, stream>>>(ypred, pmax, pmin, partials);
    reduce_mean_kernel<<<1, 1024, 0, stream>>>(partials, out);
}